// Round 10
// baseline (390.177 us; speedup 1.0000x reference)
//
#include <hip/hip_runtime.h>
#include <hip/hip_bf16.h>

#define N_NODES 50000
#define N_EDGES 800000
#define IN_C 512
#define HID_C 256
#define OUT_C 128
#define SCAN_BLOCKS 49  // ceil(50000 / 1024)

typedef short bf16x8 __attribute__((ext_vector_type(8)));
typedef float f32x4 __attribute__((ext_vector_type(4)));
typedef float f32x2 __attribute__((ext_vector_type(2)));

__device__ __forceinline__ float bf2f(unsigned short u) {
    return __uint_as_float(((unsigned)u) << 16);
}
__device__ __forceinline__ unsigned short f2bf(float f) {
    __hip_bfloat16 h = __float2bfloat16(f);
    return *(unsigned short*)&h;
}
// decode 4 fp8(e4m3) from one dword, accumulate (unweighted) into a[0..3]
__device__ __forceinline__ void acc_fp8x4(int dw, float* a) {
    f32x2 lo = __builtin_amdgcn_cvt_pk_f32_fp8(dw, false);
    f32x2 hi = __builtin_amdgcn_cvt_pk_f32_fp8(dw, true);
    a[0] += lo[0]; a[1] += lo[1]; a[2] += hi[0]; a[3] += hi[1];
}
__device__ __forceinline__ unsigned char f2fp8(float f) {
    return (unsigned char)(__builtin_amdgcn_cvt_pk_fp8_f32(f, 0.0f, 0, false) & 0xff);
}
__device__ __forceinline__ void glds16(const void* gp, void* lp) {
    __builtin_amdgcn_global_load_lds((const __attribute__((address_space(1))) void*)gp,
                                     (__attribute__((address_space(3))) void*)lp, 16, 0, 0);
}

// ---------------------------------------------------------------- CSR build
__global__ void zero_counts_kernel(int* __restrict__ counts) {
    int i = blockIdx.x * blockDim.x + threadIdx.x;
    if (i < N_NODES) counts[i] = 0;
}

__global__ void count_kernel(const int* __restrict__ ei, int* __restrict__ counts) {
    int e = blockIdx.x * blockDim.x + threadIdx.x;
    if (e < N_EDGES) atomicAdd(&counts[ei[N_EDGES + e]], 1);
}

__global__ __launch_bounds__(256) void scan_part_kernel(const int* __restrict__ counts,
                                                        int* __restrict__ excl,
                                                        int* __restrict__ bsums) {
    __shared__ int tsum[256];
    const int t = threadIdx.x;
    const int base = blockIdx.x * 1024 + t * 4;
    int v[4];
    int s = 0;
#pragma unroll
    for (int j = 0; j < 4; j++) {
        int idx = base + j;
        v[j] = (idx < N_NODES) ? counts[idx] : 0;
        s += v[j];
    }
    tsum[t] = s;
    __syncthreads();
    for (int off = 1; off < 256; off <<= 1) {
        int add = (t >= off) ? tsum[t - off] : 0;
        __syncthreads();
        tsum[t] += add;
        __syncthreads();
    }
    int run = tsum[t] - s;
#pragma unroll
    for (int j = 0; j < 4; j++) {
        int idx = base + j;
        if (idx < N_NODES) excl[idx] = run;
        run += v[j];
    }
    if (t == 255) bsums[blockIdx.x] = tsum[255];
}

// wave-parallel exclusive scan of the 49 block sums
__global__ void scan_sums_kernel(int* __restrict__ bsums) {
    int ln = threadIdx.x;  // 64 threads = 1 wave
    int v = (ln < SCAN_BLOCKS) ? bsums[ln] : 0;
    for (int off = 1; off < 64; off <<= 1) {
        int u = __shfl_up(v, off, 64);
        if (ln >= off) v += u;
    }
    int excl = __shfl_up(v, 1, 64);
    if (ln == 0) excl = 0;
    if (ln < SCAN_BLOCKS) bsums[ln] = excl;
}

__global__ void add_dinv_kernel(int* __restrict__ offsets, const int* __restrict__ bsums,
                                int* __restrict__ woff, const int* __restrict__ counts,
                                float* __restrict__ dinv) {
    int i = blockIdx.x * blockDim.x + threadIdx.x;
    if (i < N_NODES) {
        int o = offsets[i] + bsums[i >> 10];
        offsets[i] = o;
        woff[i] = o;
        dinv[i] = rsqrtf(1.0f + (float)counts[i]);
    }
    if (i == 0) offsets[N_NODES] = N_EDGES;
}

// edge record is just src (4B): norm is folded into prescaled rows (GEMM
// epilogues scale row r by dinv[r]) and the dst factor applied at gather end.
__global__ void fill_kernel(const int* __restrict__ ei, int* __restrict__ woff,
                            int* __restrict__ sedge) {
    int e = blockIdx.x * blockDim.x + threadIdx.x;
    if (e < N_EDGES) {
        int s = ei[e];
        int d = ei[N_EDGES + e];
        int pos = atomicAdd(&woff[d], 1);
        sedge[pos] = s;
    }
}

// ---------------------------------------------------------------- casts
// WT[n][k] = bf16(W[k][n]); grid covers N*K exactly
__global__ __launch_bounds__(256) void tcast_kernel(const float* __restrict__ W,
                                                    unsigned short* __restrict__ WT,
                                                    int K, int N) {
    int idx = blockIdx.x * 256 + threadIdx.x;
    int n = idx / K, k = idx - n * K;
    WT[idx] = f2bf(W[(size_t)k * N + n]);
}

// ---------------------- fused cast+GEMM layer 1, counted-vmcnt pipeline ---
// H1[M,256](fp8) = fp8( dinv[row] * (bf16(x[M,512]) @ W1T[256,512]^T) )
// 128x128 tile, BK=32, 4 waves, double-buffered LDS. KEY CHANGE vs R8:
// raw s_barrier + inline-asm s_waitcnt vmcnt(6) (counted, never 0 in the
// steady state) instead of __syncthreads() (which drains vmcnt to 0 every
// step — the m97 ceiling). 2-deep prefetch: loads for step t are issued at
// step t-2 and have a full compute phase + drain period to complete.
__global__ __launch_bounds__(256) void gemm1_f32(const float* __restrict__ x,
                                                 const unsigned short* __restrict__ BT,
                                                 unsigned char* __restrict__ C,
                                                 const float* __restrict__ dinv) {
    __shared__ float As[2][128 * 32];           // fp32, swizzled as in R8
    __shared__ unsigned short Bs[2][128 * 32];  // bf16, swizzled as in R8

    const int tid = threadIdx.x;
    const int w = tid >> 6;
    const int ln = tid & 63;
    const int br = blockIdx.y * 128;
    const int bc = blockIdx.x * 128;

    const int quad = ln >> 4;
    const int l16 = ln & 15;
    const int wr = (w >> 1) * 64;
    const int wc = (w & 1) * 64;

    // staging geometry (same as R8; pre-swizzled global source columns)
    const int arl = ln >> 3;
    const int acs = ((ln & 7) ^ arl) << 2;
    const int brl = ln >> 2;
    const int bus = ((ln & 3) ^ (brl & 3)) << 3;

    // read-side swizzled offsets (same as R8)
    const int r7 = l16 & 7;
    const int o1 = (quad << 3) ^ (r7 << 2);
    const int bso = (quad ^ (l16 & 3)) << 3;

    f32x4 acc[4][4];
#pragma unroll
    for (int mt = 0; mt < 4; mt++)
#pragma unroll
        for (int nt = 0; nt < 4; nt++) acc[mt][nt] = (f32x4){0.f, 0.f, 0.f, 0.f};

    // issue one K-step's 6 async loads (4 A + 2 B) into buffer `half`
    auto STAGE = [&](int step, int half) {
        const int kk = step * 32;
#pragma unroll
        for (int i = 0; i < 4; i++) {
            int gr = br + (i * 4 + w) * 8 + arl;
            gr = gr < N_NODES ? gr : N_NODES - 1;  // clamp (dup read, stores guarded)
            glds16(x + (size_t)gr * IN_C + kk + acs,
                   (char*)&As[half][0] + (i * 4 + w) * 1024 + ln * 16);
        }
#pragma unroll
        for (int tt = 0; tt < 2; tt++) {
            int c = w + tt * 4;
            glds16(BT + (size_t)(bc + c * 16 + brl) * IN_C + kk + bus,
                   (char*)&Bs[half][0] + c * 1024 + ln * 16);
        }
    };

    // ---- prologue: 2-deep prefetch (12 loads in flight)
    STAGE(0, 0);
    STAGE(1, 1);

#pragma unroll
    for (int t = 0; t < 16; t++) {
        // wait only for the OLDER stage's 6 loads (counted; 0 only at tail)
        if (t < 15) asm volatile("s_waitcnt vmcnt(6)" ::: "memory");
        else        asm volatile("s_waitcnt vmcnt(0)" ::: "memory");
        __builtin_amdgcn_s_barrier();  // all waves' loads for this buffer done

        const int half = t & 1;
        bf16x8 af[4], bfr[4];
#pragma unroll
        for (int mt = 0; mt < 4; mt++) {
            const float* p = &As[half][0] + (wr + mt * 16 + l16) * 32;
            float4 fa = *(const float4*)(p + o1);        // logical q*8+0..3
            float4 fb = *(const float4*)(p + (o1 ^ 4));  // logical q*8+4..7
            bf16x8 a8;
            a8[0] = (short)f2bf(fa.x); a8[1] = (short)f2bf(fa.y);
            a8[2] = (short)f2bf(fa.z); a8[3] = (short)f2bf(fa.w);
            a8[4] = (short)f2bf(fb.x); a8[5] = (short)f2bf(fb.y);
            a8[6] = (short)f2bf(fb.z); a8[7] = (short)f2bf(fb.w);
            af[mt] = a8;
        }
#pragma unroll
        for (int nt = 0; nt < 4; nt++)
            bfr[nt] = *(const bf16x8*)&Bs[half][(wc + nt * 16 + l16) * 32 + bso];
#pragma unroll
        for (int mt = 0; mt < 4; mt++)
#pragma unroll
            for (int nt = 0; nt < 4; nt++)
                acc[mt][nt] = __builtin_amdgcn_mfma_f32_16x16x32_bf16(af[mt], bfr[nt],
                                                                      acc[mt][nt], 0, 0, 0);
        __builtin_amdgcn_s_barrier();  // all waves done READING this buffer
        if (t + 2 < 16) STAGE(t + 2, half);  // refill freed buffer (6 loads)
    }

#pragma unroll
    for (int mt = 0; mt < 4; mt++) {
#pragma unroll
        for (int r = 0; r < 4; r++) {
            int gr = br + wr + mt * 16 + quad * 4 + r;
            if (gr < N_NODES) {
                float ds = dinv[gr];
#pragma unroll
                for (int nt = 0; nt < 4; nt++) {
                    int gc = bc + wc + nt * 16 + l16;
                    C[(size_t)gr * HID_C + gc] = f2fp8(ds * acc[mt][nt][r]);
                }
            }
        }
    }
}

// ------------------------------------------------------ GEMM layer 2 (2-ph)
// H2[M,128](bf16) = bf16( dinv[row] * (A1b[M,256](bf16) @ W2T[128,256]^T) )
// BM=64, BN=128 (full N -> A read once), BK=32, double-buffered, both
// operands via global_load_lds. Wave w: rows (w>>1)*32, cols (w&1)*64.
__global__ __launch_bounds__(256) void gemm2_db(const unsigned short* __restrict__ A,
                                                const unsigned short* __restrict__ BT,
                                                unsigned short* __restrict__ C,
                                                const float* __restrict__ dinv) {
    __shared__ unsigned short As[2][64 * 32];   // 2 x 4 KB
    __shared__ unsigned short Bs[2][128 * 32];  // 2 x 8 KB

    const int tid = threadIdx.x;
    const int w = tid >> 6;
    const int ln = tid & 63;
    const int br = blockIdx.x * 64;

    const int quad = ln >> 4;
    const int l16 = ln & 15;
    const int wr = (w >> 1) * 32;
    const int wc = (w & 1) * 64;

    const int ak = (tid & 3) * 8;
    const int trow = tid >> 2;  // 0..63

    int arow = br + trow;
    arow = arow < N_NODES ? arow : N_NODES - 1;  // clamp (stores guarded)
    const unsigned short* agp0 = A + (size_t)arow * HID_C + ak;

    f32x4 acc[2][4];
#pragma unroll
    for (int mt = 0; mt < 2; mt++)
#pragma unroll
        for (int nt = 0; nt < 4; nt++) acc[mt][nt] = (f32x4){0.f, 0.f, 0.f, 0.f};

    // prologue: stage k-step 0
    glds16(agp0, &As[0][tid * 8]);
#pragma unroll
    for (int tt = 0; tt < 2; tt++) {
        const unsigned short* gp = BT + (size_t)(trow + 64 * tt) * HID_C + ak;
        glds16(gp, &Bs[0][tt * 2048 + tid * 8]);
    }
    __syncthreads();

    for (int t = 0; t < 8; t++) {
        const int buf = t & 1;
        const int nxt = buf ^ 1;
        if (t < 7) {
            const int kk = (t + 1) * 32;
            glds16(agp0 + kk, &As[nxt][tid * 8]);
#pragma unroll
            for (int tt = 0; tt < 2; tt++) {
                const unsigned short* gp = BT + (size_t)(trow + 64 * tt) * HID_C + kk + ak;
                glds16(gp, &Bs[nxt][tt * 2048 + tid * 8]);
            }
        }

        bf16x8 af[2], bfr[4];
#pragma unroll
        for (int mt = 0; mt < 2; mt++)
            af[mt] = *(const bf16x8*)&As[buf][(wr + mt * 16 + l16) * 32 + quad * 8];
#pragma unroll
        for (int nt = 0; nt < 4; nt++)
            bfr[nt] = *(const bf16x8*)&Bs[buf][(wc + nt * 16 + l16) * 32 + quad * 8];
#pragma unroll
        for (int mt = 0; mt < 2; mt++)
#pragma unroll
            for (int nt = 0; nt < 4; nt++)
                acc[mt][nt] = __builtin_amdgcn_mfma_f32_16x16x32_bf16(af[mt], bfr[nt],
                                                                      acc[mt][nt], 0, 0, 0);
        __syncthreads();
    }

#pragma unroll
    for (int mt = 0; mt < 2; mt++) {
#pragma unroll
        for (int r = 0; r < 4; r++) {
            int gr = br + wr + mt * 16 + quad * 4 + r;
            if (gr < N_NODES) {
                float ds = dinv[gr];
#pragma unroll
                for (int nt = 0; nt < 4; nt++) {
                    int gc = wc + nt * 16 + l16;
                    C[(size_t)gr * OUT_C + gc] = f2bf(ds * acc[mt][nt][r]);
                }
            }
        }
    }
}

// ------------------------------------------------------- gather aggregation
// Layer-1 gather: H rows are fp8(e4m3), prescaled by dinv[src]. One wave per
// node, 2 groups of 32 lanes; lane covers 8 channels (8B fp8 load).
// out = bf16( relu( dinv[node] * (self' + sum_e row'[src]) + bias ) )
__global__ __launch_bounds__(256) void gather1_fp8(const int* __restrict__ offsets,
                                                   const int* __restrict__ sedge,
                                                   const unsigned char* __restrict__ H,
                                                   const float* __restrict__ dinv,
                                                   const float* __restrict__ bias,
                                                   unsigned short* __restrict__ out) {
    const int node = blockIdx.x * 4 + (threadIdx.x >> 6);
    if (node >= N_NODES) return;
    const int ln = threadIdx.x & 63;
    const int g = ln >> 5;   // 2 groups
    const int l = ln & 31;
    const int c0 = l * 8;

    float acc[8] = {};
    if (g == 0) {  // self term exactly once (row already has dinv[node] folded)
        uint2 d = *(const uint2*)&H[(size_t)node * HID_C + c0];
        acc_fp8x4((int)d.x, acc);
        acc_fp8x4((int)d.y, acc + 4);
    }

    int k = offsets[node] + g;
    const int k1 = offsets[node + 1];
    for (; k + 6 < k1; k += 8) {  // 4-deep unroll, group stride 2
        int s0 = sedge[k], s1 = sedge[k + 2], s2 = sedge[k + 4], s3 = sedge[k + 6];
        uint2 d0 = *(const uint2*)&H[(size_t)s0 * HID_C + c0];
        uint2 d1 = *(const uint2*)&H[(size_t)s1 * HID_C + c0];
        uint2 d2 = *(const uint2*)&H[(size_t)s2 * HID_C + c0];
        uint2 d3 = *(const uint2*)&H[(size_t)s3 * HID_C + c0];
        acc_fp8x4((int)d0.x, acc); acc_fp8x4((int)d0.y, acc + 4);
        acc_fp8x4((int)d1.x, acc); acc_fp8x4((int)d1.y, acc + 4);
        acc_fp8x4((int)d2.x, acc); acc_fp8x4((int)d2.y, acc + 4);
        acc_fp8x4((int)d3.x, acc); acc_fp8x4((int)d3.y, acc + 4);
    }
    for (; k < k1; k += 2) {
        int s0 = sedge[k];
        uint2 d0 = *(const uint2*)&H[(size_t)s0 * HID_C + c0];
        acc_fp8x4((int)d0.x, acc);
        acc_fp8x4((int)d0.y, acc + 4);
    }

    // combine the 2 group partials
#pragma unroll
    for (int j = 0; j < 8; j++) acc[j] += __shfl_xor(acc[j], 32, 64);

    if (g == 0) {
        const float di = dinv[node];
        bf16x8 o;
#pragma unroll
        for (int j = 0; j < 8; j++)
            o[j] = (short)f2bf(fmaxf(di * acc[j] + bias[c0 + j], 0.0f));
        *(bf16x8*)&out[(size_t)node * HID_C + c0] = o;
    }
}

// Layer-2 gather: H rows bf16, prescaled by dinv[src]. 4 groups of 16 lanes;
// lane covers 8 channels (16B bf16 load). fp32 output.
__global__ __launch_bounds__(256) void gather2_bf16(const int* __restrict__ offsets,
                                                    const int* __restrict__ sedge,
                                                    const unsigned short* __restrict__ H,
                                                    const float* __restrict__ dinv,
                                                    const float* __restrict__ bias,
                                                    float* __restrict__ out) {
    const int node = blockIdx.x * 4 + (threadIdx.x >> 6);
    if (node >= N_NODES) return;
    const int ln = threadIdx.x & 63;
    const int g = ln >> 4;   // 4 groups
    const int l = ln & 15;
    const int c0 = l * 8;

    float acc[8] = {};
    if (g == 0) {
        bf16x8 h = *(const bf16x8*)&H[(size_t)node * OUT_C + c0];
#pragma unroll
        for (int j = 0; j < 8; j++) acc[j] = bf2f((unsigned short)h[j]);
    }

    int k = offsets[node] + g;
    const int k1 = offsets[node + 1];
    for (; k + 12 < k1; k += 16) {  // 4-deep unroll, group stride 4
        int s0 = sedge[k], s1 = sedge[k + 4], s2 = sedge[k + 8], s3 = sedge[k + 12];
        bf16x8 h0 = *(const bf16x8*)&H[(size_t)s0 * OUT_C + c0];
        bf16x8 h1 = *(const bf16x8*)&H[(size_t)s1 * OUT_C + c0];
        bf16x8 h2 = *(const bf16x8*)&H[(size_t)s2 * OUT_C + c0];
        bf16x8 h3 = *(const bf16x8*)&H[(size_t)s3 * OUT_C + c0];
#pragma unroll
        for (int j = 0; j < 8; j++) {
            acc[j] += bf2f((unsigned short)h0[j]);
            acc[j] += bf2f((unsigned short)h1[j]);
            acc[j] += bf2f((unsigned short)h2[j]);
            acc[j] += bf2f((unsigned short)h3[j]);
        }
    }
    for (; k < k1; k += 4) {
        int s0 = sedge[k];
        bf16x8 h0 = *(const bf16x8*)&H[(size_t)s0 * OUT_C + c0];
#pragma unroll
        for (int j = 0; j < 8; j++) acc[j] += bf2f((unsigned short)h0[j]);
    }

#pragma unroll
    for (int m = 16; m < 64; m <<= 1) {
#pragma unroll
        for (int j = 0; j < 8; j++) acc[j] += __shfl_xor(acc[j], m, 64);
    }

    if (g == 0) {
        const float di = dinv[node];
        float o[8];
#pragma unroll
        for (int j = 0; j < 8; j++) o[j] = di * acc[j] + bias[c0 + j];
        *(float4*)&out[(size_t)node * OUT_C + c0] = make_float4(o[0], o[1], o[2], o[3]);
        *(float4*)&out[(size_t)node * OUT_C + c0 + 4] = make_float4(o[4], o[5], o[6], o[7]);
    }
}

// ---------------------------------------------------------------- launcher
extern "C" void kernel_launch(void* const* d_in, const int* in_sizes, int n_in,
                              void* d_out, int out_size, void* d_ws, size_t ws_size,
                              hipStream_t stream) {
    const float* x  = (const float*)d_in[0];
    const int*   ei = (const int*)d_in[1];
    const float* W1 = (const float*)d_in[2];
    const float* b1 = (const float*)d_in[3];
    const float* W2 = (const float*)d_in[4];
    const float* b2 = (const float*)d_in[5];
    float* out = (float*)d_out;

    // workspace layout (4-byte words), same as known-good R2 (68.3 MiB).
    int*   counts     = (int*)d_ws;                          // 50048
    int*   offsets    = counts + 50048;                      // 50052 (+sentinel)
    int*   woff       = offsets + 50052;                     // 50048
    int*   bsums      = woff + 50048;                        // 64
    float* dinv       = (float*)(bsums + 64);                // 50048
    int*   sedge      = (int*)(dinv + 50048);                // 800000 (src only)
    unsigned short* W1T = (unsigned short*)(sedge + 800000);          // 131072 sh
    unsigned short* W2T = W1T + 131072;                               // 32768 sh
    unsigned short* xb  = W2T + 32768;                                // 25.6M sh region
    unsigned char*  H1  = (unsigned char*)(xb + (size_t)N_NODES * IN_C);  // 12.8MB fp8
    unsigned short* A1b = xb;                                         // overlay (bf16)
    unsigned short* H2  = xb + (size_t)N_NODES * HID_C;               // overlay (bf16)

    // CSR build + norm
    zero_counts_kernel<<<(N_NODES + 255) / 256, 256, 0, stream>>>(counts);
    count_kernel<<<(N_EDGES + 255) / 256, 256, 0, stream>>>(ei, counts);
    scan_part_kernel<<<SCAN_BLOCKS, 256, 0, stream>>>(counts, offsets, bsums);
    scan_sums_kernel<<<1, 64, 0, stream>>>(bsums);
    add_dinv_kernel<<<(N_NODES + 255) / 256, 256, 0, stream>>>(offsets, bsums, woff, counts, dinv);
    fill_kernel<<<(N_EDGES + 255) / 256, 256, 0, stream>>>(ei, woff, sedge);

    // weight casts (tiny)
    tcast_kernel<<<(IN_C * HID_C) / 256, 256, 0, stream>>>(W1, W1T, IN_C, HID_C);
    tcast_kernel<<<(HID_C * OUT_C) / 256, 256, 0, stream>>>(W2, W2T, HID_C, OUT_C);

    // layer 1: H1 = fp8( dinv[row] * (bf16(x) @ W1T^T) )  (counted-vmcnt pipeline)
    {
        dim3 grid(HID_C / 128, (N_NODES + 127) / 128);
        gemm1_f32<<<grid, 256, 0, stream>>>(x, W1T, H1, dinv);
    }
    gather1_fp8<<<(N_NODES + 3) / 4, 256, 0, stream>>>(offsets, sedge, H1, dinv, b1, A1b);

    // layer 2: H2 = bf16( dinv[row] * (A1b @ W2T^T) )
    gemm2_db<<<(N_NODES + 63) / 64, 256, 0, stream>>>(A1b, W2T, H2, dinv);
    gather2_bf16<<<(N_NODES + 3) / 4, 256, 0, stream>>>(offsets, sedge, H2, dinv, b2, out);
}

// Round 11
// 383.606 us; speedup vs baseline: 1.0171x; 1.0171x over previous
//
#include <hip/hip_runtime.h>
#include <hip/hip_bf16.h>

#define N_NODES 50000
#define N_EDGES 800000
#define IN_C 512
#define HID_C 256
#define OUT_C 128
#define SCAN_BLOCKS 49  // ceil(50000 / 1024)

typedef short bf16x8 __attribute__((ext_vector_type(8)));
typedef float f32x4 __attribute__((ext_vector_type(4)));
typedef float f32x2 __attribute__((ext_vector_type(2)));

__device__ __forceinline__ float bf2f(unsigned short u) {
    return __uint_as_float(((unsigned)u) << 16);
}
__device__ __forceinline__ unsigned short f2bf(float f) {
    __hip_bfloat16 h = __float2bfloat16(f);
    return *(unsigned short*)&h;
}
// decode 4 fp8(e4m3) from one dword, accumulate (unweighted) into a[0..3]
__device__ __forceinline__ void acc_fp8x4(int dw, float* a) {
    f32x2 lo = __builtin_amdgcn_cvt_pk_f32_fp8(dw, false);
    f32x2 hi = __builtin_amdgcn_cvt_pk_f32_fp8(dw, true);
    a[0] += lo[0]; a[1] += lo[1]; a[2] += hi[0]; a[3] += hi[1];
}
__device__ __forceinline__ unsigned char f2fp8(float f) {
    return (unsigned char)(__builtin_amdgcn_cvt_pk_fp8_f32(f, 0.0f, 0, false) & 0xff);
}
__device__ __forceinline__ void glds16(const void* gp, void* lp) {
    __builtin_amdgcn_global_load_lds((const __attribute__((address_space(1))) void*)gp,
                                     (__attribute__((address_space(3))) void*)lp, 16, 0, 0);
}

// ---------------------------------------------------------------- CSR build
__global__ void zero_counts_kernel(int* __restrict__ counts) {
    int i = blockIdx.x * blockDim.x + threadIdx.x;
    if (i < N_NODES) counts[i] = 0;
}

__global__ void count_kernel(const int* __restrict__ ei, int* __restrict__ counts) {
    int e = blockIdx.x * blockDim.x + threadIdx.x;
    if (e < N_EDGES) atomicAdd(&counts[ei[N_EDGES + e]], 1);
}

__global__ __launch_bounds__(256) void scan_part_kernel(const int* __restrict__ counts,
                                                        int* __restrict__ excl,
                                                        int* __restrict__ bsums) {
    __shared__ int tsum[256];
    const int t = threadIdx.x;
    const int base = blockIdx.x * 1024 + t * 4;
    int v[4];
    int s = 0;
#pragma unroll
    for (int j = 0; j < 4; j++) {
        int idx = base + j;
        v[j] = (idx < N_NODES) ? counts[idx] : 0;
        s += v[j];
    }
    tsum[t] = s;
    __syncthreads();
    for (int off = 1; off < 256; off <<= 1) {
        int add = (t >= off) ? tsum[t - off] : 0;
        __syncthreads();
        tsum[t] += add;
        __syncthreads();
    }
    int run = tsum[t] - s;
#pragma unroll
    for (int j = 0; j < 4; j++) {
        int idx = base + j;
        if (idx < N_NODES) excl[idx] = run;
        run += v[j];
    }
    if (t == 255) bsums[blockIdx.x] = tsum[255];
}

// wave-parallel exclusive scan of the 49 block sums
__global__ void scan_sums_kernel(int* __restrict__ bsums) {
    int ln = threadIdx.x;  // 64 threads = 1 wave
    int v = (ln < SCAN_BLOCKS) ? bsums[ln] : 0;
    for (int off = 1; off < 64; off <<= 1) {
        int u = __shfl_up(v, off, 64);
        if (ln >= off) v += u;
    }
    int excl = __shfl_up(v, 1, 64);
    if (ln == 0) excl = 0;
    if (ln < SCAN_BLOCKS) bsums[ln] = excl;
}

__global__ void add_dinv_kernel(int* __restrict__ offsets, const int* __restrict__ bsums,
                                int* __restrict__ woff, const int* __restrict__ counts,
                                float* __restrict__ dinv) {
    int i = blockIdx.x * blockDim.x + threadIdx.x;
    if (i < N_NODES) {
        int o = offsets[i] + bsums[i >> 10];
        offsets[i] = o;
        woff[i] = o;
        dinv[i] = rsqrtf(1.0f + (float)counts[i]);
    }
    if (i == 0) offsets[N_NODES] = N_EDGES;
}

// edge record is just src (4B): norm is folded into prescaled rows (GEMM
// epilogues scale row r by dinv[r]) and the dst factor applied at gather end.
__global__ void fill_kernel(const int* __restrict__ ei, int* __restrict__ woff,
                            int* __restrict__ sedge) {
    int e = blockIdx.x * blockDim.x + threadIdx.x;
    if (e < N_EDGES) {
        int s = ei[e];
        int d = ei[N_EDGES + e];
        int pos = atomicAdd(&woff[d], 1);
        sedge[pos] = s;
    }
}

// ------------------------------------------------- merged weight transposes
// W1T[n][k] = bf16(W1[k][n]) (256x512) then W2T[n][k] = bf16(W2[k][n])
// (128x256), one launch. Grid covers (IN_C*HID_C + HID_C*OUT_C)/256 exactly.
__global__ __launch_bounds__(256) void tcast2_kernel(const float* __restrict__ W1,
                                                     const float* __restrict__ W2,
                                                     unsigned short* __restrict__ W1T,
                                                     unsigned short* __restrict__ W2T) {
    int idx = blockIdx.x * 256 + threadIdx.x;
    if (idx < IN_C * HID_C) {
        int n = idx / IN_C, k = idx - n * IN_C;
        W1T[idx] = f2bf(W1[(size_t)k * HID_C + n]);
    } else {
        int j = idx - IN_C * HID_C;
        int n = j / HID_C, k = j - n * HID_C;
        W2T[j] = f2bf(W2[(size_t)k * OUT_C + n]);
    }
}

// ------------------------- fused cast+GEMM layer 1, high-occupancy retile --
// H1[M,256](fp8) = fp8( dinv[row] * (bf16(x[M,512]) @ W1T[256,512]^T) )
// BM=64 x BN=128, BK=32 -> grid (2,782) = 1564 blocks = 6.1 blocks/CU
// (2x every prior variant: R3..R10 all ran 782 blocks = 12 waves/CU and all
// measured 72 us regardless of sync/staging/swizzle -> TLP-starved).
// 16 KB LDS single-buffered; same proven staging + swizzle scheme as R8/R10;
// plain 2-barrier loop (sync structure measured immaterial). 4 waves: wave w
// owns rows (w>>1)*32..+32, cols (w&1)*64..+64 (acc 2x4, 32 VGPR).
__global__ __launch_bounds__(256) void gemm1_f32(const float* __restrict__ x,
                                                 const unsigned short* __restrict__ BT,
                                                 unsigned char* __restrict__ C,
                                                 const float* __restrict__ dinv) {
    __shared__ float As[64 * 32];            // 8 KB fp32, phys col = c ^ ((row&7)<<2)
    __shared__ unsigned short Bs[128 * 32];  // 8 KB bf16, phys 16B-unit = u ^ (row&3)

    const int tid = threadIdx.x;
    const int w = tid >> 6;
    const int ln = tid & 63;
    const int br = blockIdx.y * 64;
    const int bc = blockIdx.x * 128;

    const int quad = ln >> 4;
    const int l16 = ln & 15;
    const int wr = (w >> 1) * 32;
    const int wc = (w & 1) * 64;

    // staging geometry (identical scheme to R8/R10, correctness-proven)
    const int arl = ln >> 3;                 // row within 8-row A chunk
    const int acs = ((ln & 7) ^ arl) << 2;   // pre-swizzled fp32 col
    const int brl = ln >> 2;                 // row within 16-row B chunk
    const int bus = ((ln & 3) ^ (brl & 3)) << 3;  // pre-swizzled short unit

    // read-side swizzled offsets (identical to R8/R10)
    const int r7 = l16 & 7;
    const int o1 = (quad << 3) ^ (r7 << 2);
    const int bso = (quad ^ (l16 & 3)) << 3;

    f32x4 acc[2][4];
#pragma unroll
    for (int mt = 0; mt < 2; mt++)
#pragma unroll
        for (int nt = 0; nt < 4; nt++) acc[mt][nt] = (f32x4){0.f, 0.f, 0.f, 0.f};

    for (int kk = 0; kk < IN_C; kk += 32) {
        // A: 2 async ops/wave (8 rows each) -> 64 rows
#pragma unroll
        for (int t = 0; t < 2; t++) {
            int gr = br + (w * 2 + t) * 8 + arl;
            gr = gr < N_NODES ? gr : N_NODES - 1;  // clamp (dup read, stores guarded)
            glds16(x + (size_t)gr * IN_C + kk + acs,
                   (char*)As + (w * 2 + t) * 1024 + ln * 16);
        }
        // B: 2 async ops/wave (16 rows each) -> 128 rows; BN=128, no clamp
#pragma unroll
        for (int t = 0; t < 2; t++) {
            int c = w + t * 4;
            glds16(BT + (size_t)(bc + c * 16 + brl) * IN_C + kk + bus,
                   (char*)Bs + c * 1024 + ln * 16);
        }
        __syncthreads();

        bf16x8 af[2], bfr[4];
#pragma unroll
        for (int mt = 0; mt < 2; mt++) {
            const float* p = As + (wr + mt * 16 + l16) * 32;
            float4 fa = *(const float4*)(p + o1);        // logical q*8+0..3
            float4 fb = *(const float4*)(p + (o1 ^ 4));  // logical q*8+4..7
            bf16x8 a8;
            a8[0] = (short)f2bf(fa.x); a8[1] = (short)f2bf(fa.y);
            a8[2] = (short)f2bf(fa.z); a8[3] = (short)f2bf(fa.w);
            a8[4] = (short)f2bf(fb.x); a8[5] = (short)f2bf(fb.y);
            a8[6] = (short)f2bf(fb.z); a8[7] = (short)f2bf(fb.w);
            af[mt] = a8;
        }
#pragma unroll
        for (int nt = 0; nt < 4; nt++)
            bfr[nt] = *(const bf16x8*)&Bs[(wc + nt * 16 + l16) * 32 + bso];
#pragma unroll
        for (int mt = 0; mt < 2; mt++)
#pragma unroll
            for (int nt = 0; nt < 4; nt++)
                acc[mt][nt] = __builtin_amdgcn_mfma_f32_16x16x32_bf16(af[mt], bfr[nt],
                                                                      acc[mt][nt], 0, 0, 0);
        __syncthreads();
    }

#pragma unroll
    for (int mt = 0; mt < 2; mt++) {
#pragma unroll
        for (int r = 0; r < 4; r++) {
            int gr = br + wr + mt * 16 + quad * 4 + r;
            if (gr < N_NODES) {
                float ds = dinv[gr];
#pragma unroll
                for (int nt = 0; nt < 4; nt++) {
                    int gc = bc + wc + nt * 16 + l16;
                    C[(size_t)gr * HID_C + gc] = f2fp8(ds * acc[mt][nt][r]);
                }
            }
        }
    }
}

// ------------------------------------------------------ GEMM layer 2 (2-ph)
// H2[M,128](bf16) = bf16( dinv[row] * (A1b[M,256](bf16) @ W2T[128,256]^T) )
// BM=64, BN=128 (full N -> A read once), BK=32, double-buffered, both
// operands via global_load_lds. Wave w: rows (w>>1)*32, cols (w&1)*64.
__global__ __launch_bounds__(256) void gemm2_db(const unsigned short* __restrict__ A,
                                                const unsigned short* __restrict__ BT,
                                                unsigned short* __restrict__ C,
                                                const float* __restrict__ dinv) {
    __shared__ unsigned short As[2][64 * 32];   // 2 x 4 KB
    __shared__ unsigned short Bs[2][128 * 32];  // 2 x 8 KB

    const int tid = threadIdx.x;
    const int w = tid >> 6;
    const int ln = tid & 63;
    const int br = blockIdx.x * 64;

    const int quad = ln >> 4;
    const int l16 = ln & 15;
    const int wr = (w >> 1) * 32;
    const int wc = (w & 1) * 64;

    const int ak = (tid & 3) * 8;
    const int trow = tid >> 2;  // 0..63

    int arow = br + trow;
    arow = arow < N_NODES ? arow : N_NODES - 1;  // clamp (stores guarded)
    const unsigned short* agp0 = A + (size_t)arow * HID_C + ak;

    f32x4 acc[2][4];
#pragma unroll
    for (int mt = 0; mt < 2; mt++)
#pragma unroll
        for (int nt = 0; nt < 4; nt++) acc[mt][nt] = (f32x4){0.f, 0.f, 0.f, 0.f};

    // prologue: stage k-step 0
    glds16(agp0, &As[0][tid * 8]);
#pragma unroll
    for (int tt = 0; tt < 2; tt++) {
        const unsigned short* gp = BT + (size_t)(trow + 64 * tt) * HID_C + ak;
        glds16(gp, &Bs[0][tt * 2048 + tid * 8]);
    }
    __syncthreads();

    for (int t = 0; t < 8; t++) {
        const int buf = t & 1;
        const int nxt = buf ^ 1;
        if (t < 7) {
            const int kk = (t + 1) * 32;
            glds16(agp0 + kk, &As[nxt][tid * 8]);
#pragma unroll
            for (int tt = 0; tt < 2; tt++) {
                const unsigned short* gp = BT + (size_t)(trow + 64 * tt) * HID_C + kk + ak;
                glds16(gp, &Bs[nxt][tt * 2048 + tid * 8]);
            }
        }

        bf16x8 af[2], bfr[4];
#pragma unroll
        for (int mt = 0; mt < 2; mt++)
            af[mt] = *(const bf16x8*)&As[buf][(wr + mt * 16 + l16) * 32 + quad * 8];
#pragma unroll
        for (int nt = 0; nt < 4; nt++)
            bfr[nt] = *(const bf16x8*)&Bs[buf][(wc + nt * 16 + l16) * 32 + quad * 8];
#pragma unroll
        for (int mt = 0; mt < 2; mt++)
#pragma unroll
            for (int nt = 0; nt < 4; nt++)
                acc[mt][nt] = __builtin_amdgcn_mfma_f32_16x16x32_bf16(af[mt], bfr[nt],
                                                                      acc[mt][nt], 0, 0, 0);
        __syncthreads();
    }

#pragma unroll
    for (int mt = 0; mt < 2; mt++) {
#pragma unroll
        for (int r = 0; r < 4; r++) {
            int gr = br + wr + mt * 16 + quad * 4 + r;
            if (gr < N_NODES) {
                float ds = dinv[gr];
#pragma unroll
                for (int nt = 0; nt < 4; nt++) {
                    int gc = wc + nt * 16 + l16;
                    C[(size_t)gr * OUT_C + gc] = f2bf(ds * acc[mt][nt][r]);
                }
            }
        }
    }
}

// ------------------------------------------------------- gather aggregation
// Layer-1 gather: H rows are fp8(e4m3), prescaled by dinv[src]. One wave per
// node, 2 groups of 32 lanes; lane covers 8 channels (8B fp8 load).
// out = bf16( relu( dinv[node] * (self' + sum_e row'[src]) + bias ) )
__global__ __launch_bounds__(256) void gather1_fp8(const int* __restrict__ offsets,
                                                   const int* __restrict__ sedge,
                                                   const unsigned char* __restrict__ H,
                                                   const float* __restrict__ dinv,
                                                   const float* __restrict__ bias,
                                                   unsigned short* __restrict__ out) {
    const int node = blockIdx.x * 4 + (threadIdx.x >> 6);
    if (node >= N_NODES) return;
    const int ln = threadIdx.x & 63;
    const int g = ln >> 5;   // 2 groups
    const int l = ln & 31;
    const int c0 = l * 8;

    float acc[8] = {};
    if (g == 0) {  // self term exactly once (row already has dinv[node] folded)
        uint2 d = *(const uint2*)&H[(size_t)node * HID_C + c0];
        acc_fp8x4((int)d.x, acc);
        acc_fp8x4((int)d.y, acc + 4);
    }

    int k = offsets[node] + g;
    const int k1 = offsets[node + 1];
    for (; k + 6 < k1; k += 8) {  // 4-deep unroll, group stride 2
        int s0 = sedge[k], s1 = sedge[k + 2], s2 = sedge[k + 4], s3 = sedge[k + 6];
        uint2 d0 = *(const uint2*)&H[(size_t)s0 * HID_C + c0];
        uint2 d1 = *(const uint2*)&H[(size_t)s1 * HID_C + c0];
        uint2 d2 = *(const uint2*)&H[(size_t)s2 * HID_C + c0];
        uint2 d3 = *(const uint2*)&H[(size_t)s3 * HID_C + c0];
        acc_fp8x4((int)d0.x, acc); acc_fp8x4((int)d0.y, acc + 4);
        acc_fp8x4((int)d1.x, acc); acc_fp8x4((int)d1.y, acc + 4);
        acc_fp8x4((int)d2.x, acc); acc_fp8x4((int)d2.y, acc + 4);
        acc_fp8x4((int)d3.x, acc); acc_fp8x4((int)d3.y, acc + 4);
    }
    for (; k < k1; k += 2) {
        int s0 = sedge[k];
        uint2 d0 = *(const uint2*)&H[(size_t)s0 * HID_C + c0];
        acc_fp8x4((int)d0.x, acc);
        acc_fp8x4((int)d0.y, acc + 4);
    }

    // combine the 2 group partials
#pragma unroll
    for (int j = 0; j < 8; j++) acc[j] += __shfl_xor(acc[j], 32, 64);

    if (g == 0) {
        const float di = dinv[node];
        bf16x8 o;
#pragma unroll
        for (int j = 0; j < 8; j++)
            o[j] = (short)f2bf(fmaxf(di * acc[j] + bias[c0 + j], 0.0f));
        *(bf16x8*)&out[(size_t)node * HID_C + c0] = o;
    }
}

// Layer-2 gather: H rows bf16, prescaled by dinv[src]. 4 groups of 16 lanes;
// lane covers 8 channels (16B bf16 load). fp32 output.
__global__ __launch_bounds__(256) void gather2_bf16(const int* __restrict__ offsets,
                                                    const int* __restrict__ sedge,
                                                    const unsigned short* __restrict__ H,
                                                    const float* __restrict__ dinv,
                                                    const float* __restrict__ bias,
                                                    float* __restrict__ out) {
    const int node = blockIdx.x * 4 + (threadIdx.x >> 6);
    if (node >= N_NODES) return;
    const int ln = threadIdx.x & 63;
    const int g = ln >> 4;   // 4 groups
    const int l = ln & 15;
    const int c0 = l * 8;

    float acc[8] = {};
    if (g == 0) {
        bf16x8 h = *(const bf16x8*)&H[(size_t)node * OUT_C + c0];
#pragma unroll
        for (int j = 0; j < 8; j++) acc[j] = bf2f((unsigned short)h[j]);
    }

    int k = offsets[node] + g;
    const int k1 = offsets[node + 1];
    for (; k + 12 < k1; k += 16) {  // 4-deep unroll, group stride 4
        int s0 = sedge[k], s1 = sedge[k + 4], s2 = sedge[k + 8], s3 = sedge[k + 12];
        bf16x8 h0 = *(const bf16x8*)&H[(size_t)s0 * OUT_C + c0];
        bf16x8 h1 = *(const bf16x8*)&H[(size_t)s1 * OUT_C + c0];
        bf16x8 h2 = *(const bf16x8*)&H[(size_t)s2 * OUT_C + c0];
        bf16x8 h3 = *(const bf16x8*)&H[(size_t)s3 * OUT_C + c0];
#pragma unroll
        for (int j = 0; j < 8; j++) {
            acc[j] += bf2f((unsigned short)h0[j]);
            acc[j] += bf2f((unsigned short)h1[j]);
            acc[j] += bf2f((unsigned short)h2[j]);
            acc[j] += bf2f((unsigned short)h3[j]);
        }
    }
    for (; k < k1; k += 4) {
        int s0 = sedge[k];
        bf16x8 h0 = *(const bf16x8*)&H[(size_t)s0 * OUT_C + c0];
#pragma unroll
        for (int j = 0; j < 8; j++) acc[j] += bf2f((unsigned short)h0[j]);
    }

#pragma unroll
    for (int m = 16; m < 64; m <<= 1) {
#pragma unroll
        for (int j = 0; j < 8; j++) acc[j] += __shfl_xor(acc[j], m, 64);
    }

    if (g == 0) {
        const float di = dinv[node];
        float o[8];
#pragma unroll
        for (int j = 0; j < 8; j++) o[j] = di * acc[j] + bias[c0 + j];
        *(float4*)&out[(size_t)node * OUT_C + c0] = make_float4(o[0], o[1], o[2], o[3]);
        *(float4*)&out[(size_t)node * OUT_C + c0 + 4] = make_float4(o[4], o[5], o[6], o[7]);
    }
}

// ---------------------------------------------------------------- launcher
extern "C" void kernel_launch(void* const* d_in, const int* in_sizes, int n_in,
                              void* d_out, int out_size, void* d_ws, size_t ws_size,
                              hipStream_t stream) {
    const float* x  = (const float*)d_in[0];
    const int*   ei = (const int*)d_in[1];
    const float* W1 = (const float*)d_in[2];
    const float* b1 = (const float*)d_in[3];
    const float* W2 = (const float*)d_in[4];
    const float* b2 = (const float*)d_in[5];
    float* out = (float*)d_out;

    // workspace layout (4-byte words), same as known-good R2 (68.3 MiB).
    int*   counts     = (int*)d_ws;                          // 50048
    int*   offsets    = counts + 50048;                      // 50052 (+sentinel)
    int*   woff       = offsets + 50052;                     // 50048
    int*   bsums      = woff + 50048;                        // 64
    float* dinv       = (float*)(bsums + 64);                // 50048
    int*   sedge      = (int*)(dinv + 50048);                // 800000 (src only)
    unsigned short* W1T = (unsigned short*)(sedge + 800000);          // 131072 sh
    unsigned short* W2T = W1T + 131072;                               // 32768 sh
    unsigned short* xb  = W2T + 32768;                                // 25.6M sh region
    unsigned char*  H1  = (unsigned char*)(xb + (size_t)N_NODES * IN_C);  // 12.8MB fp8
    unsigned short* A1b = xb;                                         // overlay (bf16)
    unsigned short* H2  = xb + (size_t)N_NODES * HID_C;               // overlay (bf16)

    // CSR build + norm
    zero_counts_kernel<<<(N_NODES + 255) / 256, 256, 0, stream>>>(counts);
    count_kernel<<<(N_EDGES + 255) / 256, 256, 0, stream>>>(ei, counts);
    scan_part_kernel<<<SCAN_BLOCKS, 256, 0, stream>>>(counts, offsets, bsums);
    scan_sums_kernel<<<1, 64, 0, stream>>>(bsums);
    add_dinv_kernel<<<(N_NODES + 255) / 256, 256, 0, stream>>>(offsets, bsums, woff, counts, dinv);
    fill_kernel<<<(N_EDGES + 255) / 256, 256, 0, stream>>>(ei, woff, sedge);

    // weight transposes (merged, one launch)
    tcast2_kernel<<<(IN_C * HID_C + HID_C * OUT_C) / 256, 256, 0, stream>>>(W1, W2, W1T, W2T);

    // layer 1: H1 = fp8( dinv[row] * (bf16(x) @ W1T^T) )  (high-occupancy retile)
    {
        dim3 grid(HID_C / 128, (N_NODES + 63) / 64);
        gemm1_f32<<<grid, 256, 0, stream>>>(x, W1T, H1, dinv);
    }
    gather1_fp8<<<(N_NODES + 3) / 4, 256, 0, stream>>>(offsets, sedge, H1, dinv, b1, A1b);

    // layer 2: H2 = bf16( dinv[row] * (A1b @ W2T^T) )
    gemm2_db<<<(N_NODES + 63) / 64, 256, 0, stream>>>(A1b, W2T, H2, dinv);
    gather2_bf16<<<(N_NODES + 3) / 4, 256, 0, stream>>>(offsets, sedge, H2, dinv, b2, out);
}